// Round 7
// baseline (453.203 us; speedup 1.0000x reference)
//
#include <hip/hip_runtime.h>
#include <hip/hip_bf16.h>
#include <math.h>

#define NPART 8

typedef __attribute__((ext_vector_type(8))) short bf16x8;
typedef __attribute__((ext_vector_type(4))) float f32x4;

__device__ __forceinline__ float lrelu(float v) { return fmaxf(v, 0.2f * v); }

__device__ __forceinline__ unsigned fenc(float f) {
    unsigned u = __float_as_uint(f);
    return (u & 0x80000000u) ? ~u : (u | 0x80000000u);
}
__device__ __forceinline__ float fdec(unsigned u) {
    return __uint_as_float((u & 0x80000000u) ? (u & 0x7FFFFFFFu) : ~u);
}
__device__ __forceinline__ unsigned short f2bf(float f) {
    union { __hip_bfloat16 b; unsigned short u; } cv;
    cv.b = __float2bfloat16(f);
    return cv.u;
}
__device__ __forceinline__ float bflo(unsigned u) { return __uint_as_float(u << 16); }
__device__ __forceinline__ float bfhi(unsigned u) { return __uint_as_float(u & 0xFFFF0000u); }

// ---- setup_all: conv x->bf16, W->Wt bf16, gmax seed, hb dummy row, + deg_count (deg pre-zeroed) ----

__global__ void setup_all(const float* __restrict__ x,
                          const float* __restrict__ W1, const float* __restrict__ W2,
                          const float* __restrict__ W3,
                          unsigned short* __restrict__ xb,
                          unsigned short* __restrict__ Wt1, unsigned short* __restrict__ Wt2,
                          unsigned short* __restrict__ Wt3,
                          const int* __restrict__ ei, int E,
                          int* __restrict__ deg, unsigned* __restrict__ gmax,
                          unsigned short* __restrict__ hb, int N, int GX, int pn) {
    int b = blockIdx.x, t = threadIdx.x;
    if (b < GX) {                                   // role A: x conversion + small inits
        int i = b * 256 + t;
        if (i < N * 32) {
            float4 v = ((const float4*)x)[i];
            ushort4 o;
            o.x = f2bf(v.x); o.y = f2bf(v.y); o.z = f2bf(v.z); o.w = f2bf(v.w);
            ((ushort4*)xb)[i] = o;
        }
        if (i < 12) gmax[i] = fenc(-1e30f);
        if (i < 64) ((unsigned*)hb)[(size_t)N * 64 + i] = 0;   // dummy row N = 0
        return;
    }
    if (b < GX + 192) {                             // role B: W transpose-convert
        int j = (b - GX) * 256 + t;
        int mm = j >> 14, e = j & 16383;
        const float* W = (mm == 0) ? W1 : (mm == 1) ? W2 : W3;
        unsigned short* Wt = (mm == 0) ? Wt1 : (mm == 1) ? Wt2 : Wt3;
        int k = e >> 7, c = e & 127;
        Wt[c * 128 + k] = f2bf(W[e]);               // Wt[col][k]
        return;
    }
    {                                               // role C: degree count (XCD-partitioned)
        int bb = b - GX - 192;
        int part = bb & (NPART - 1);
        int chunk = bb >> 3;
        int stride = 256 * 256;                     // 2048 blocks / 8 parts * 256 thr
        int lo = part * pn, hi = min(lo + pn, N);
        for (int i = chunk * 256 + t; i < E; i += stride) {
            int d = ei[E + i];
            if (d >= lo && d < hi) atomicAdd(&deg[d], 1);
        }
    }
}

// ---- single-block scan: padded offsets + cursor + self-loop & pad writes ----

__global__ __launch_bounds__(1024) void scan_all(const int* __restrict__ deg, int N,
                                                 int* __restrict__ offs, int* __restrict__ cursor,
                                                 int* __restrict__ srcs) {
    __shared__ int ws[16];
    int t = threadIdx.x;
    int chunk = (N + 1023) / 1024;
    int lo = t * chunk, hi = min(lo + chunk, N);
    int sum = 0;
    for (int i = lo; i < hi; i++) sum += (deg[i] + 4) & ~3;    // (+1 self-loop, pad x4)
    int lane = t & 63, w = t >> 6;
    int val = sum;
    for (int o = 1; o < 64; o <<= 1) {
        int u = __shfl_up(val, o);
        if (lane >= o) val += u;
    }
    if (lane == 63) ws[w] = val;
    __syncthreads();
    if (w == 0 && lane < 16) {
        int orig = ws[lane];
        int v = orig;
        for (int o = 1; o < 16; o <<= 1) {
            int u = __shfl_up(v, o);
            if (lane >= o) v += u;
        }
        ws[lane] = v - orig;                       // exclusive wave base
    }
    __syncthreads();
    int off = ws[w] + (val - sum);                 // exclusive thread base
    for (int i = lo; i < hi; i++) {
        int dr = deg[i] + 1;
        int pad = (dr + 3) & ~3;
        offs[i + 1] = off + pad;
        cursor[i] = off + 1;                       // slot 0 = self-loop
        srcs[off] = i;
        for (int k = off + dr; k < off + pad; k++) srcs[k] = N;   // dummy pads
        off += pad;
    }
    if (t == 0) offs[0] = 0;
}

// ---- scatter (XCD-partitioned) ----

__global__ void scatter_part(const int* __restrict__ ei, int E, int N,
                             int* cursor, int* srcs, int pn) {
    int part = blockIdx.x & (NPART - 1);
    int nb = gridDim.x >> 3;
    int chunk = blockIdx.x >> 3;
    int stride = nb * blockDim.x;
    int lo = part * pn, hi = min(lo + pn, N);
    for (int i = chunk * blockDim.x + threadIdx.x; i < E; i += stride) {
        int d = ei[E + i];
        if (d >= lo && d < hi) {
            int pos = atomicAdd(&cursor[d], 1);
            srcs[pos] = ei[i];
        }
    }
}

// ---- MFMA GEMM + fused logits + per-head global max. wave: 16 rows x 128 cols, K=128 ----

template <int H>
__global__ __launch_bounds__(256) void gemm_fused(const unsigned short* __restrict__ xb,
                                                  const unsigned short* __restrict__ Wt,
                                                  const float* __restrict__ a_s,
                                                  const float* __restrict__ a_d,
                                                  unsigned short* __restrict__ hb,
                                                  float* __restrict__ asb,
                                                  float* __restrict__ adb,
                                                  unsigned* __restrict__ gmax, int N) {
    constexpr int HH = (H == 4) ? 4 : 1;
    __shared__ float smax[4][HH];
    int t = threadIdx.x;
    int wave = t >> 6, lane = t & 63;
    int lrow = lane & 15;
    int kg = lane >> 4;
    int row0 = blockIdx.x * 64 + wave * 16;
    int arow = min(row0 + lrow, N - 1);
    const bf16x8* ap = (const bf16x8*)(xb + (size_t)arow * 128 + kg * 8);

    f32x4 acc[8];
#pragma unroll
    for (int ct = 0; ct < 8; ct++) acc[ct] = (f32x4)0.f;
#pragma unroll
    for (int kk = 0; kk < 4; kk++) {
        bf16x8 a = ap[kk * 4];
#pragma unroll
        for (int ct = 0; ct < 8; ct++) {
            const bf16x8* bp = (const bf16x8*)(Wt + (size_t)(ct * 16 + lrow) * 128 + kk * 32 + kg * 8);
            acc[ct] = __builtin_amdgcn_mfma_f32_16x16x32_bf16(a, *bp, acc[ct], 0, 0, 0);
        }
    }
    // D layout: row = kg*4 + reg, col = ct*16 + lrow
    int orow = row0 + kg * 4;
#pragma unroll
    for (int reg = 0; reg < 4; reg++) {
        int r = orow + reg;
        if (r < N) {
#pragma unroll
            for (int ct = 0; ct < 8; ct++)
                hb[(size_t)r * 128 + ct * 16 + lrow] = f2bf(acc[ct][reg]);
        }
    }
    // fused logits from fp32 accumulators
    float ps[4][HH], pd[4][HH];
#pragma unroll
    for (int reg = 0; reg < 4; reg++)
#pragma unroll
        for (int hd = 0; hd < HH; hd++) { ps[reg][hd] = 0.f; pd[reg][hd] = 0.f; }
#pragma unroll
    for (int ct = 0; ct < 8; ct++) {
        int hd = (H == 4) ? (ct >> 1) : 0;
        float asv = a_s[ct * 16 + lrow];
        float adv = a_d[ct * 16 + lrow];
#pragma unroll
        for (int reg = 0; reg < 4; reg++) {
            ps[reg][hd] += acc[ct][reg] * asv;
            pd[reg][hd] += acc[ct][reg] * adv;
        }
    }
    for (int o = 1; o < 16; o <<= 1) {
#pragma unroll
        for (int reg = 0; reg < 4; reg++)
#pragma unroll
            for (int hd = 0; hd < HH; hd++) {
                ps[reg][hd] += __shfl_xor(ps[reg][hd], o);
                pd[reg][hd] += __shfl_xor(pd[reg][hd], o);
            }
    }
    if (lrow < HH) {
        int hd = lrow;
#pragma unroll
        for (int reg = 0; reg < 4; reg++) {
            int r = orow + reg;
            if (r < N) {
                asb[(size_t)r * H + hd] = ps[reg][hd];
                adb[(size_t)r * H + hd] = pd[reg][hd];
            }
        }
    }
    // per-head global max: wave reduce -> block reduce -> 1 atomic per head
    float wm[HH];
#pragma unroll
    for (int hd = 0; hd < HH; hd++) {
        float m = fmaxf(fmaxf(ps[0][hd], ps[1][hd]), fmaxf(ps[2][hd], ps[3][hd]));
        m = fmaxf(m, __shfl_xor(m, 16));
        m = fmaxf(m, __shfl_xor(m, 32));
        wm[hd] = m;
    }
    if (lane == 0)
#pragma unroll
        for (int hd = 0; hd < HH; hd++) smax[wave][hd] = wm[hd];
    __syncthreads();
    if (t < HH) {
        float m = fmaxf(fmaxf(smax[0][t], smax[1][t]), fmaxf(smax[2][t], smax[3][t]));
        atomicMax(&gmax[t], fenc(m));
    }
    if (blockIdx.x == 0 && t == 0) {
#pragma unroll
        for (int hd = 0; hd < HH; hd++) asb[(size_t)N * H + hd] = -1e30f;  // dummy -> p=0
    }
}

// ---- aggregation: QUARTER-wave per dst (16 lanes x 16 B = 256 B row), padded CSR ----

template <int H, bool RELU, bool OUTBF>
__global__ __launch_bounds__(256) void aggregate8(const unsigned short* __restrict__ hb,
                                                  const int* __restrict__ offs,
                                                  const int* __restrict__ srcs,
                                                  const float* __restrict__ asb,
                                                  const float* __restrict__ adb,
                                                  const unsigned* __restrict__ gmax,
                                                  const float* __restrict__ bias,
                                                  void* __restrict__ outv, int N) {
    int n = (blockIdx.x * 256 + threadIdx.x) >> 4;     // quarter-wave id = node
    if (n >= N) return;
    unsigned l = threadIdx.x & 15;
    unsigned ht = (H == 4) ? (l >> 2) : 0;
    float adn = adb[(unsigned)n * H + ht];
    float m = lrelu(fdec(gmax[ht]) + adn);
    int beg = offs[n];
    int nb = (offs[n + 1] - beg) >> 2;
    const uint4* hrow = (const uint4*)hb;               // 16 B per lane, 16 uint4/row
    const int4* sp = (const int4*)(srcs + beg);
    float a0 = 0.f, a1 = 0.f, a2 = 0.f, a3 = 0.f;
    float a4 = 0.f, a5 = 0.f, a6 = 0.f, a7 = 0.f, den = 0.f;
    int4 sv = sp[0];
    for (int b = 0; b < nb; b++) {
        int4 nxt = (b + 1 < nb) ? sp[b + 1] : sv;
        unsigned s0 = sv.x, s1 = sv.y, s2 = sv.z, s3 = sv.w;
        uint4 u0 = hrow[s0 * 16u + l];
        uint4 u1 = hrow[s1 * 16u + l];
        uint4 u2 = hrow[s2 * 16u + l];
        uint4 u3 = hrow[s3 * 16u + l];
        float e0 = asb[s0 * H + ht], e1 = asb[s1 * H + ht];
        float e2 = asb[s2 * H + ht], e3 = asb[s3 * H + ht];
        float p0 = __expf(lrelu(e0 + adn) - m);
        float p1 = __expf(lrelu(e1 + adn) - m);
        float p2 = __expf(lrelu(e2 + adn) - m);
        float p3 = __expf(lrelu(e3 + adn) - m);
        a0 += p0 * bflo(u0.x); a1 += p0 * bfhi(u0.x); a2 += p0 * bflo(u0.y); a3 += p0 * bfhi(u0.y);
        a4 += p0 * bflo(u0.z); a5 += p0 * bfhi(u0.z); a6 += p0 * bflo(u0.w); a7 += p0 * bfhi(u0.w);
        a0 += p1 * bflo(u1.x); a1 += p1 * bfhi(u1.x); a2 += p1 * bflo(u1.y); a3 += p1 * bfhi(u1.y);
        a4 += p1 * bflo(u1.z); a5 += p1 * bfhi(u1.z); a6 += p1 * bflo(u1.w); a7 += p1 * bfhi(u1.w);
        a0 += p2 * bflo(u2.x); a1 += p2 * bfhi(u2.x); a2 += p2 * bflo(u2.y); a3 += p2 * bfhi(u2.y);
        a4 += p2 * bflo(u2.z); a5 += p2 * bfhi(u2.z); a6 += p2 * bflo(u2.w); a7 += p2 * bfhi(u2.w);
        a0 += p3 * bflo(u3.x); a1 += p3 * bfhi(u3.x); a2 += p3 * bflo(u3.y); a3 += p3 * bfhi(u3.y);
        a4 += p3 * bflo(u3.z); a5 += p3 * bfhi(u3.z); a6 += p3 * bflo(u3.w); a7 += p3 * bfhi(u3.w);
        den += p0 + p1 + p2 + p3;
        sv = nxt;
    }
    float inv = 1.f / (den + 1e-16f);
    unsigned c = l * 8;
    float4 bv0 = *(const float4*)&bias[c];
    float4 bv1 = *(const float4*)&bias[c + 4];
    float o0 = a0 * inv + bv0.x, o1 = a1 * inv + bv0.y;
    float o2 = a2 * inv + bv0.z, o3 = a3 * inv + bv0.w;
    float o4 = a4 * inv + bv1.x, o5 = a5 * inv + bv1.y;
    float o6 = a6 * inv + bv1.z, o7 = a7 * inv + bv1.w;
    if (RELU) {
        o0 = fmaxf(o0, 0.f); o1 = fmaxf(o1, 0.f); o2 = fmaxf(o2, 0.f); o3 = fmaxf(o3, 0.f);
        o4 = fmaxf(o4, 0.f); o5 = fmaxf(o5, 0.f); o6 = fmaxf(o6, 0.f); o7 = fmaxf(o7, 0.f);
    }
    if (OUTBF) {
        uint4 st;
        st.x = (unsigned)f2bf(o0) | ((unsigned)f2bf(o1) << 16);
        st.y = (unsigned)f2bf(o2) | ((unsigned)f2bf(o3) << 16);
        st.z = (unsigned)f2bf(o4) | ((unsigned)f2bf(o5) << 16);
        st.w = (unsigned)f2bf(o6) | ((unsigned)f2bf(o7) << 16);
        *(uint4*)&((unsigned short*)outv)[(size_t)n * 128 + c] = st;
    } else {
        float* op = (float*)outv + (size_t)n * 128 + c;
        float4 s0; s0.x = o0; s0.y = o1; s0.z = o2; s0.w = o3;
        float4 s1; s1.x = o4; s1.y = o5; s1.z = o6; s1.w = o7;
        *(float4*)op = s0;
        *(float4*)(op + 4) = s1;
    }
}

// ---------------- launch ----------------

extern "C" void kernel_launch(void* const* d_in, const int* in_sizes, int n_in,
                              void* d_out, int out_size, void* d_ws, size_t ws_size,
                              hipStream_t stream) {
    const float* x   = (const float*)d_in[0];
    const int*   ei  = (const int*)d_in[1];
    const float* W1  = (const float*)d_in[2];
    const float* as1 = (const float*)d_in[3];
    const float* ad1 = (const float*)d_in[4];
    const float* b1  = (const float*)d_in[5];
    const float* W2  = (const float*)d_in[6];
    const float* as2 = (const float*)d_in[7];
    const float* ad2 = (const float*)d_in[8];
    const float* b2  = (const float*)d_in[9];
    const float* W3  = (const float*)d_in[10];
    const float* as3 = (const float*)d_in[11];
    const float* ad3 = (const float*)d_in[12];
    const float* b3  = (const float*)d_in[13];

    const int N = in_sizes[0] / 128;
    const int E = in_sizes[1] / 2;
    const int PN = (N + NPART - 1) / NPART;

    char* w = (char*)d_ws;
    size_t woff = 0;
    auto alloc = [&](size_t bytes) -> void* {
        void* p = w + woff;
        woff = (woff + bytes + 255) & ~(size_t)255;
        return p;
    };
    int*      deg    = (int*)alloc((size_t)(N + 1) * 4);
    int*      offs   = (int*)alloc((size_t)(N + 1) * 4);
    int*      cursor = (int*)alloc((size_t)(N + 1) * 4);
    int*      srcs   = (int*)alloc(((size_t)E + 4 * (size_t)N + 8) * 4);
    float*    asb    = (float*)alloc((size_t)(N + 1) * 4 * 4);
    float*    adb    = (float*)alloc((size_t)(N + 1) * 4 * 4);
    unsigned* gmax   = (unsigned*)alloc(16 * 4);
    unsigned short* hb  = (unsigned short*)alloc((size_t)(N + 1) * 128 * 2);
    unsigned short* xb  = (unsigned short*)alloc((size_t)N * 128 * 2);
    unsigned short* Wt1 = (unsigned short*)alloc(128 * 128 * 2);
    unsigned short* Wt2 = (unsigned short*)alloc(128 * 128 * 2);
    unsigned short* Wt3 = (unsigned short*)alloc(128 * 128 * 2);
    float* outf = (float*)d_out;

    // 1) zero degree counts (graph-capturable async memset)
    hipMemsetAsync(deg, 0, (size_t)N * 4, stream);

    // 2) fused setup: conversions + inits + degree count
    const int GX = (N * 32 + 255) / 256;
    setup_all<<<GX + 192 + 2048, 256, 0, stream>>>(x, W1, W2, W3, xb, Wt1, Wt2, Wt3,
                                                   ei, E, deg, gmax, hb, N, GX, PN);

    // 3) single-block padded scan (+self-loop seeds, +dummy pads)
    scan_all<<<1, 1024, 0, stream>>>(deg, N, offs, cursor, srcs);

    // 4) scatter
    scatter_part<<<2048, 256, 0, stream>>>(ei, E, N, cursor, srcs, PN);

    const int gb = (N + 63) / 64;
    const int ga = (N * 16 + 255) / 256;

    // Layer 1: xb -> hb -> xb (bf16, relu)
    gemm_fused<4><<<gb, 256, 0, stream>>>(xb, Wt1, as1, ad1, hb, asb, adb, gmax + 0, N);
    aggregate8<4, true, true><<<ga, 256, 0, stream>>>(hb, offs, srcs, asb, adb, gmax + 0, b1, xb, N);

    // Layer 2: xb -> hb -> xb (bf16, relu)
    gemm_fused<4><<<gb, 256, 0, stream>>>(xb, Wt2, as2, ad2, hb, asb, adb, gmax + 4, N);
    aggregate8<4, true, true><<<ga, 256, 0, stream>>>(hb, offs, srcs, asb, adb, gmax + 4, b2, xb, N);

    // Layer 3: xb -> hb -> d_out (fp32, H=1, no relu)
    gemm_fused<1><<<gb, 256, 0, stream>>>(xb, Wt3, as3, ad3, hb, asb, adb, gmax + 8, N);
    aggregate8<1, false, false><<<ga, 256, 0, stream>>>(hb, offs, srcs, asb, adb, gmax + 8, b3, outf, N);
}

// Round 8
// 305.565 us; speedup vs baseline: 1.4832x; 1.4832x over previous
//
#include <hip/hip_runtime.h>
#include <hip/hip_bf16.h>
#include <math.h>

#define NPART 8

typedef __attribute__((ext_vector_type(8))) short bf16x8;
typedef __attribute__((ext_vector_type(4))) float f32x4;

__device__ __forceinline__ float lrelu(float v) { return fmaxf(v, 0.2f * v); }

__device__ __forceinline__ unsigned fenc(float f) {
    unsigned u = __float_as_uint(f);
    return (u & 0x80000000u) ? ~u : (u | 0x80000000u);
}
__device__ __forceinline__ float fdec(unsigned u) {
    return __uint_as_float((u & 0x80000000u) ? (u & 0x7FFFFFFFu) : ~u);
}
__device__ __forceinline__ unsigned short f2bf(float f) {
    union { __hip_bfloat16 b; unsigned short u; } cv;
    cv.b = __float2bfloat16(f);
    return cv.u;
}
__device__ __forceinline__ float bflo(unsigned u) { return __uint_as_float(u << 16); }
__device__ __forceinline__ float bfhi(unsigned u) { return __uint_as_float(u & 0xFFFF0000u); }

// ---- setup_all: conv x->bf16, W->Wt bf16, gmax seed, hb dummy row, + deg_count (deg pre-zeroed) ----

__global__ void setup_all(const float* __restrict__ x,
                          const float* __restrict__ W1, const float* __restrict__ W2,
                          const float* __restrict__ W3,
                          unsigned short* __restrict__ xb,
                          unsigned short* __restrict__ Wt1, unsigned short* __restrict__ Wt2,
                          unsigned short* __restrict__ Wt3,
                          const int* __restrict__ ei, int E,
                          int* __restrict__ deg, unsigned* __restrict__ gmax,
                          unsigned short* __restrict__ hb, int N, int GX, int pn) {
    int b = blockIdx.x, t = threadIdx.x;
    if (b < GX) {                                   // role A: x conversion + small inits
        int i = b * 256 + t;
        if (i < N * 32) {
            float4 v = ((const float4*)x)[i];
            ushort4 o;
            o.x = f2bf(v.x); o.y = f2bf(v.y); o.z = f2bf(v.z); o.w = f2bf(v.w);
            ((ushort4*)xb)[i] = o;
        }
        if (i < 12) gmax[i] = fenc(-1e30f);
        if (i < 64) ((unsigned*)hb)[(size_t)N * 64 + i] = 0;   // dummy row N = 0
        return;
    }
    if (b < GX + 192) {                             // role B: W transpose-convert
        int j = (b - GX) * 256 + t;
        int mm = j >> 14, e = j & 16383;
        const float* W = (mm == 0) ? W1 : (mm == 1) ? W2 : W3;
        unsigned short* Wt = (mm == 0) ? Wt1 : (mm == 1) ? Wt2 : Wt3;
        int k = e >> 7, c = e & 127;
        Wt[c * 128 + k] = f2bf(W[e]);               // Wt[col][k]
        return;
    }
    {                                               // role C: degree count (XCD-partitioned)
        int bb = b - GX - 192;
        int part = bb & (NPART - 1);
        int chunk = bb >> 3;
        int stride = 256 * 256;
        int lo = part * pn, hi = min(lo + pn, N);
        for (int i = chunk * 256 + t; i < E; i += stride) {
            int d = ei[E + i];
            if (d >= lo && d < hi) atomicAdd(&deg[d], 1);
        }
    }
}

// ---- multi-block padded scan (3 kernels, ~10 us total) ----

__global__ void scan_partial(const int* __restrict__ deg, int N, int* bsum) {
    __shared__ int sm[256];
    int t = threadIdx.x;
    int i = blockIdx.x * 256 + t;
    int v = (i < N) ? ((deg[i] + 4) & ~3) : 0;     // +1 self-loop, pad x4
    sm[t] = v; __syncthreads();
    for (int o = 1; o < 256; o <<= 1) {
        int u = (t >= o) ? sm[t - o] : 0;
        __syncthreads();
        sm[t] += u;
        __syncthreads();
    }
    if (t == 255) bsum[blockIdx.x] = sm[255];
}

__global__ void scan_bsums(int* bsum, int nb) {
    __shared__ int sm[256];
    int t = threadIdx.x;
    int v = (t < nb) ? bsum[t] : 0;
    sm[t] = v; __syncthreads();
    for (int o = 1; o < 256; o <<= 1) {
        int u = (t >= o) ? sm[t - o] : 0;
        __syncthreads();
        sm[t] += u;
        __syncthreads();
    }
    if (t < nb) bsum[t] = sm[t] - v;               // exclusive
}

// writes offs, cursor, self-loop at segment start, dummy pads (idx N) at tail
__global__ void scan_final(const int* __restrict__ deg, const int* __restrict__ bsum,
                           int N, int* offs, int* cursor, int* srcs) {
    __shared__ int sm[256];
    int t = threadIdx.x;
    int i = blockIdx.x * 256 + t;
    int dr = (i < N) ? (deg[i] + 1) : 0;           // incl. self-loop
    int v = (dr + 3) & ~3;
    sm[t] = v; __syncthreads();
    for (int o = 1; o < 256; o <<= 1) {
        int u = (t >= o) ? sm[t - o] : 0;
        __syncthreads();
        sm[t] += u;
        __syncthreads();
    }
    int incl = sm[t] + bsum[blockIdx.x];
    if (i < N) {
        int beg = incl - v;
        offs[i + 1] = incl;
        cursor[i] = beg + 1;                       // slot 0 = self-loop
        srcs[beg] = i;
        for (int k = beg + dr; k < incl; k++) srcs[k] = N;   // dummy pads
    }
    if (i == 0) offs[0] = 0;
}

// ---- scatter (XCD-partitioned) ----

__global__ void scatter_part(const int* __restrict__ ei, int E, int N,
                             int* cursor, int* srcs, int pn) {
    int part = blockIdx.x & (NPART - 1);
    int nb = gridDim.x >> 3;
    int chunk = blockIdx.x >> 3;
    int stride = nb * blockDim.x;
    int lo = part * pn, hi = min(lo + pn, N);
    for (int i = chunk * blockDim.x + threadIdx.x; i < E; i += stride) {
        int d = ei[E + i];
        if (d >= lo && d < hi) {
            int pos = atomicAdd(&cursor[d], 1);
            srcs[pos] = ei[i];
        }
    }
}

// ---- MFMA GEMM + fused logits + per-head global max. wave: 16 rows x 128 cols, K=128 ----

template <int H>
__global__ __launch_bounds__(256) void gemm_fused(const unsigned short* __restrict__ xb,
                                                  const unsigned short* __restrict__ Wt,
                                                  const float* __restrict__ a_s,
                                                  const float* __restrict__ a_d,
                                                  unsigned short* __restrict__ hb,
                                                  float* __restrict__ asb,
                                                  float* __restrict__ adb,
                                                  unsigned* __restrict__ gmax, int N) {
    constexpr int HH = (H == 4) ? 4 : 1;
    __shared__ float smax[4][HH];
    int t = threadIdx.x;
    int wave = t >> 6, lane = t & 63;
    int lrow = lane & 15;
    int kg = lane >> 4;
    int row0 = blockIdx.x * 64 + wave * 16;
    int arow = min(row0 + lrow, N - 1);
    const bf16x8* ap = (const bf16x8*)(xb + (size_t)arow * 128 + kg * 8);

    f32x4 acc[8];
#pragma unroll
    for (int ct = 0; ct < 8; ct++) acc[ct] = (f32x4)0.f;
#pragma unroll
    for (int kk = 0; kk < 4; kk++) {
        bf16x8 a = ap[kk * 4];
#pragma unroll
        for (int ct = 0; ct < 8; ct++) {
            const bf16x8* bp = (const bf16x8*)(Wt + (size_t)(ct * 16 + lrow) * 128 + kk * 32 + kg * 8);
            acc[ct] = __builtin_amdgcn_mfma_f32_16x16x32_bf16(a, *bp, acc[ct], 0, 0, 0);
        }
    }
    // D layout: row = kg*4 + reg, col = ct*16 + lrow
    int orow = row0 + kg * 4;
#pragma unroll
    for (int reg = 0; reg < 4; reg++) {
        int r = orow + reg;
        if (r < N) {
#pragma unroll
            for (int ct = 0; ct < 8; ct++)
                hb[(size_t)r * 128 + ct * 16 + lrow] = f2bf(acc[ct][reg]);
        }
    }
    // fused logits from fp32 accumulators
    float ps[4][HH], pd[4][HH];
#pragma unroll
    for (int reg = 0; reg < 4; reg++)
#pragma unroll
        for (int hd = 0; hd < HH; hd++) { ps[reg][hd] = 0.f; pd[reg][hd] = 0.f; }
#pragma unroll
    for (int ct = 0; ct < 8; ct++) {
        int hd = (H == 4) ? (ct >> 1) : 0;
        float asv = a_s[ct * 16 + lrow];
        float adv = a_d[ct * 16 + lrow];
#pragma unroll
        for (int reg = 0; reg < 4; reg++) {
            ps[reg][hd] += acc[ct][reg] * asv;
            pd[reg][hd] += acc[ct][reg] * adv;
        }
    }
    for (int o = 1; o < 16; o <<= 1) {
#pragma unroll
        for (int reg = 0; reg < 4; reg++)
#pragma unroll
            for (int hd = 0; hd < HH; hd++) {
                ps[reg][hd] += __shfl_xor(ps[reg][hd], o);
                pd[reg][hd] += __shfl_xor(pd[reg][hd], o);
            }
    }
    if (lrow < HH) {
        int hd = lrow;
#pragma unroll
        for (int reg = 0; reg < 4; reg++) {
            int r = orow + reg;
            if (r < N) {
                asb[(size_t)r * H + hd] = ps[reg][hd];
                adb[(size_t)r * H + hd] = pd[reg][hd];
            }
        }
    }
    // per-head global max: wave reduce -> block reduce -> 1 atomic per head
    float wm[HH];
#pragma unroll
    for (int hd = 0; hd < HH; hd++) {
        float m = fmaxf(fmaxf(ps[0][hd], ps[1][hd]), fmaxf(ps[2][hd], ps[3][hd]));
        m = fmaxf(m, __shfl_xor(m, 16));
        m = fmaxf(m, __shfl_xor(m, 32));
        wm[hd] = m;
    }
    if (lane == 0)
#pragma unroll
        for (int hd = 0; hd < HH; hd++) smax[wave][hd] = wm[hd];
    __syncthreads();
    if (t < HH) {
        float m = fmaxf(fmaxf(smax[0][t], smax[1][t]), fmaxf(smax[2][t], smax[3][t]));
        atomicMax(&gmax[t], fenc(m));
    }
    if (blockIdx.x == 0 && t == 0) {
#pragma unroll
        for (int hd = 0; hd < HH; hd++) asb[(size_t)N * H + hd] = -1e30f;  // dummy -> p=0
    }
}

// ---- aggregation: QUARTER-wave per dst (16 lanes x 16 B = 256 B row), padded CSR ----

template <int H, bool RELU, bool OUTBF>
__global__ __launch_bounds__(256) void aggregate8(const unsigned short* __restrict__ hb,
                                                  const int* __restrict__ offs,
                                                  const int* __restrict__ srcs,
                                                  const float* __restrict__ asb,
                                                  const float* __restrict__ adb,
                                                  const unsigned* __restrict__ gmax,
                                                  const float* __restrict__ bias,
                                                  void* __restrict__ outv, int N) {
    int n = (blockIdx.x * 256 + threadIdx.x) >> 4;     // quarter-wave id = node
    if (n >= N) return;
    unsigned l = threadIdx.x & 15;
    unsigned ht = (H == 4) ? (l >> 2) : 0;
    float adn = adb[(unsigned)n * H + ht];
    float m = lrelu(fdec(gmax[ht]) + adn);
    int beg = offs[n];
    int nb = (offs[n + 1] - beg) >> 2;
    const uint4* hrow = (const uint4*)hb;               // 16 B per lane, 16 uint4/row
    const int4* sp = (const int4*)(srcs + beg);
    float a0 = 0.f, a1 = 0.f, a2 = 0.f, a3 = 0.f;
    float a4 = 0.f, a5 = 0.f, a6 = 0.f, a7 = 0.f, den = 0.f;
    int4 sv = sp[0];
    for (int b = 0; b < nb; b++) {
        int4 nxt = (b + 1 < nb) ? sp[b + 1] : sv;
        unsigned s0 = sv.x, s1 = sv.y, s2 = sv.z, s3 = sv.w;
        uint4 u0 = hrow[s0 * 16u + l];
        uint4 u1 = hrow[s1 * 16u + l];
        uint4 u2 = hrow[s2 * 16u + l];
        uint4 u3 = hrow[s3 * 16u + l];
        float e0 = asb[s0 * H + ht], e1 = asb[s1 * H + ht];
        float e2 = asb[s2 * H + ht], e3 = asb[s3 * H + ht];
        float p0 = __expf(lrelu(e0 + adn) - m);
        float p1 = __expf(lrelu(e1 + adn) - m);
        float p2 = __expf(lrelu(e2 + adn) - m);
        float p3 = __expf(lrelu(e3 + adn) - m);
        a0 += p0 * bflo(u0.x); a1 += p0 * bfhi(u0.x); a2 += p0 * bflo(u0.y); a3 += p0 * bfhi(u0.y);
        a4 += p0 * bflo(u0.z); a5 += p0 * bfhi(u0.z); a6 += p0 * bflo(u0.w); a7 += p0 * bfhi(u0.w);
        a0 += p1 * bflo(u1.x); a1 += p1 * bfhi(u1.x); a2 += p1 * bflo(u1.y); a3 += p1 * bfhi(u1.y);
        a4 += p1 * bflo(u1.z); a5 += p1 * bfhi(u1.z); a6 += p1 * bflo(u1.w); a7 += p1 * bfhi(u1.w);
        a0 += p2 * bflo(u2.x); a1 += p2 * bfhi(u2.x); a2 += p2 * bflo(u2.y); a3 += p2 * bfhi(u2.y);
        a4 += p2 * bflo(u2.z); a5 += p2 * bfhi(u2.z); a6 += p2 * bflo(u2.w); a7 += p2 * bfhi(u2.w);
        a0 += p3 * bflo(u3.x); a1 += p3 * bfhi(u3.x); a2 += p3 * bflo(u3.y); a3 += p3 * bfhi(u3.y);
        a4 += p3 * bflo(u3.z); a5 += p3 * bfhi(u3.z); a6 += p3 * bflo(u3.w); a7 += p3 * bfhi(u3.w);
        den += p0 + p1 + p2 + p3;
        sv = nxt;
    }
    float inv = 1.f / (den + 1e-16f);
    unsigned c = l * 8;
    float4 bv0 = *(const float4*)&bias[c];
    float4 bv1 = *(const float4*)&bias[c + 4];
    float o0 = a0 * inv + bv0.x, o1 = a1 * inv + bv0.y;
    float o2 = a2 * inv + bv0.z, o3 = a3 * inv + bv0.w;
    float o4 = a4 * inv + bv1.x, o5 = a5 * inv + bv1.y;
    float o6 = a6 * inv + bv1.z, o7 = a7 * inv + bv1.w;
    if (RELU) {
        o0 = fmaxf(o0, 0.f); o1 = fmaxf(o1, 0.f); o2 = fmaxf(o2, 0.f); o3 = fmaxf(o3, 0.f);
        o4 = fmaxf(o4, 0.f); o5 = fmaxf(o5, 0.f); o6 = fmaxf(o6, 0.f); o7 = fmaxf(o7, 0.f);
    }
    if (OUTBF) {
        uint4 st;
        st.x = (unsigned)f2bf(o0) | ((unsigned)f2bf(o1) << 16);
        st.y = (unsigned)f2bf(o2) | ((unsigned)f2bf(o3) << 16);
        st.z = (unsigned)f2bf(o4) | ((unsigned)f2bf(o5) << 16);
        st.w = (unsigned)f2bf(o6) | ((unsigned)f2bf(o7) << 16);
        *(uint4*)&((unsigned short*)outv)[(size_t)n * 128 + c] = st;
    } else {
        float* op = (float*)outv + (size_t)n * 128 + c;
        float4 s0; s0.x = o0; s0.y = o1; s0.z = o2; s0.w = o3;
        float4 s1; s1.x = o4; s1.y = o5; s1.z = o6; s1.w = o7;
        *(float4*)op = s0;
        *(float4*)(op + 4) = s1;
    }
}

// ---------------- launch ----------------

extern "C" void kernel_launch(void* const* d_in, const int* in_sizes, int n_in,
                              void* d_out, int out_size, void* d_ws, size_t ws_size,
                              hipStream_t stream) {
    const float* x   = (const float*)d_in[0];
    const int*   ei  = (const int*)d_in[1];
    const float* W1  = (const float*)d_in[2];
    const float* as1 = (const float*)d_in[3];
    const float* ad1 = (const float*)d_in[4];
    const float* b1  = (const float*)d_in[5];
    const float* W2  = (const float*)d_in[6];
    const float* as2 = (const float*)d_in[7];
    const float* ad2 = (const float*)d_in[8];
    const float* b2  = (const float*)d_in[9];
    const float* W3  = (const float*)d_in[10];
    const float* as3 = (const float*)d_in[11];
    const float* ad3 = (const float*)d_in[12];
    const float* b3  = (const float*)d_in[13];

    const int N = in_sizes[0] / 128;
    const int E = in_sizes[1] / 2;
    const int NB = (N + 255) / 256;
    const int PN = (N + NPART - 1) / NPART;

    char* w = (char*)d_ws;
    size_t woff = 0;
    auto alloc = [&](size_t bytes) -> void* {
        void* p = w + woff;
        woff = (woff + bytes + 255) & ~(size_t)255;
        return p;
    };
    int*      deg    = (int*)alloc((size_t)(N + 1) * 4);
    int*      offs   = (int*)alloc((size_t)(N + 1) * 4);
    int*      cursor = (int*)alloc((size_t)(N + 1) * 4);
    int*      bsum   = (int*)alloc((size_t)NB * 4);
    int*      srcs   = (int*)alloc(((size_t)E + 4 * (size_t)N + 8) * 4);
    float*    asb    = (float*)alloc((size_t)(N + 1) * 4 * 4);
    float*    adb    = (float*)alloc((size_t)(N + 1) * 4 * 4);
    unsigned* gmax   = (unsigned*)alloc(16 * 4);
    unsigned short* hb  = (unsigned short*)alloc((size_t)(N + 1) * 128 * 2);
    unsigned short* xb  = (unsigned short*)alloc((size_t)N * 128 * 2);
    unsigned short* Wt1 = (unsigned short*)alloc(128 * 128 * 2);
    unsigned short* Wt2 = (unsigned short*)alloc(128 * 128 * 2);
    unsigned short* Wt3 = (unsigned short*)alloc(128 * 128 * 2);
    float* outf = (float*)d_out;

    // 1) zero degree counts (graph-capturable async memset)
    hipMemsetAsync(deg, 0, (size_t)N * 4, stream);

    // 2) fused setup: conversions + inits + degree count
    const int GX = (N * 32 + 255) / 256;
    setup_all<<<GX + 192 + 2048, 256, 0, stream>>>(x, W1, W2, W3, xb, Wt1, Wt2, Wt3,
                                                   ei, E, deg, gmax, hb, N, GX, PN);

    // 3) multi-block padded scan
    scan_partial<<<NB, 256, 0, stream>>>(deg, N, bsum);
    scan_bsums<<<1, 256, 0, stream>>>(bsum, NB);
    scan_final<<<NB, 256, 0, stream>>>(deg, bsum, N, offs, cursor, srcs);

    // 4) scatter
    scatter_part<<<2048, 256, 0, stream>>>(ei, E, N, cursor, srcs, PN);

    const int gb = (N + 63) / 64;
    const int ga = (N * 16 + 255) / 256;

    // Layer 1: xb -> hb -> xb (bf16, relu)
    gemm_fused<4><<<gb, 256, 0, stream>>>(xb, Wt1, as1, ad1, hb, asb, adb, gmax + 0, N);
    aggregate8<4, true, true><<<ga, 256, 0, stream>>>(hb, offs, srcs, asb, adb, gmax + 0, b1, xb, N);

    // Layer 2: xb -> hb -> xb (bf16, relu)
    gemm_fused<4><<<gb, 256, 0, stream>>>(xb, Wt2, as2, ad2, hb, asb, adb, gmax + 4, N);
    aggregate8<4, true, true><<<ga, 256, 0, stream>>>(hb, offs, srcs, asb, adb, gmax + 4, b2, xb, N);

    // Layer 3: xb -> hb -> d_out (fp32, H=1, no relu)
    gemm_fused<1><<<gb, 256, 0, stream>>>(xb, Wt3, as3, ad3, hb, asb, adb, gmax + 8, N);
    aggregate8<1, false, false><<<ga, 256, 0, stream>>>(hb, offs, srcs, asb, adb, gmax + 8, b3, outf, N);
}